// Round 1
// baseline (200.237 us; speedup 1.0000x reference)
//
#include <hip/hip_runtime.h>
#include <hip/hip_bf16.h>

#define NB 32      // batch
#define NT 2000    // time
#define NW 512     // width (conv output channels / hidden input)
#define NC 4       // antenna channels
#define NG 20      // groups (T / NUM_STEPS)
#define NS 100     // NUM_STEPS
#define NH 1024    // hidden
#define NO 10      // outputs
#define BETA 0.95f
#define THRESH 1.0f

// ---------------- Kernel 1: fused 1x1 conv + 100-step leaky scan ----------------
// One thread per (b,g,w). Reads x[b, g*100+s, w, 0..3] as float4 (coalesced over w).
// Only the FINAL spike matters (reference scan carries spk, ys are None).
__global__ __launch_bounds__(256) void k1_conv_scan(
    const float4* __restrict__ x,   // [B][T][W] of float4 (C=4 innermost)
    const float* __restrict__ cw,   // [4]
    const float* __restrict__ cb,   // [1]
    float* __restrict__ spk1)       // [B][G][W]
{
    int idx = blockIdx.x * 256 + threadIdx.x;      // 0 .. B*G*W-1
    int w = idx & (NW - 1);
    int g = (idx >> 9) % NG;
    int b = idx / (NG * NW);

    float w0 = cw[0], w1 = cw[1], w2 = cw[2], w3 = cw[3];
    float bias = cb[0];

    const float4* xp = x + ((size_t)(b * NT + g * NS) * NW + w);

    float mem = 0.0f;
    #pragma unroll 5
    for (int s = 0; s < NS; ++s) {
        float4 v = xp[(size_t)s * NW];
        float f = v.x * w0 + v.y * w1 + v.z * w2 + v.w * w3 + bias;
        float base = BETA * mem + f;            // base from PREVIOUS mem
        mem = (mem > THRESH) ? 0.0f : base;     // zero-reset if prev mem spiked
    }
    spk1[idx] = (mem > THRESH) ? 1.0f : 0.0f;   // final-step spike
}

// ---------------- Transpose hidden_w (1024x512 -> 512x1024) ----------------
__global__ __launch_bounds__(256) void k_transpose(
    const float* __restrict__ wsrc,  // [H][W]
    float* __restrict__ wT)          // [W][H]
{
    __shared__ float tile[32][33];
    int bk = blockIdx.x;             // 16 tiles over W
    int bh = blockIdx.y;             // 32 tiles over H
    int tx = threadIdx.x;            // 0..31
    int ty = threadIdx.y;            // 0..7
    #pragma unroll
    for (int j = 0; j < 4; ++j)
        tile[ty + j * 8][tx] = wsrc[(bh * 32 + ty + j * 8) * NW + bk * 32 + tx];
    __syncthreads();
    #pragma unroll
    for (int j = 0; j < 4; ++j)
        wT[(bk * 32 + ty + j * 8) * NH + bh * 32 + tx] = tile[tx][ty + j * 8];
}

// ---------------- Kernel 2: hidden GEMM (over g in registers) + 20-step scan ----
// One thread per (b,h). b is derived ONLY from blockIdx -> spk1 loads are
// wave-uniform scalar loads. wT reads are lane-coalesced over h.
__global__ __launch_bounds__(256) void k2_hidden_scan(
    const float* __restrict__ spk1,  // [B][G][W]
    const float* __restrict__ wT,    // [W][H]
    const float* __restrict__ hb,    // [H]
    float* __restrict__ spk2)        // [B][H]
{
    int b = blockIdx.x >> 2;                          // 4 blocks per b
    int h = ((blockIdx.x & 3) << 8) + threadIdx.x;    // 0..1023

    const float* sp = spk1 + (size_t)b * NG * NW;     // uniform base

    float acc[NG];
    #pragma unroll
    for (int g = 0; g < NG; ++g) acc[g] = 0.0f;

    for (int kk = 0; kk < NW; kk += 4) {
        float a0 = wT[(kk + 0) * NH + h];
        float a1 = wT[(kk + 1) * NH + h];
        float a2 = wT[(kk + 2) * NH + h];
        float a3 = wT[(kk + 3) * NH + h];
        #pragma unroll
        for (int g = 0; g < NG; ++g) {
            float4 u = *(const float4*)(sp + g * NW + kk);  // uniform -> s_load
            acc[g] += u.x * a0 + u.y * a1 + u.z * a2 + u.w * a3;
        }
    }

    float hbias = hb[h];
    float mem = 0.0f;
    #pragma unroll
    for (int g = 0; g < NG; ++g) {
        float xin = acc[g] + hbias;
        float base = BETA * mem + xin;
        mem = (mem > THRESH) ? 0.0f : base;
    }
    spk2[b * NH + h] = (mem > THRESH) ? 1.0f : 0.0f;
}

// ---------------- Kernel 3: output layer + softmax ----------------
__global__ __launch_bounds__(256) void k3_out(
    const float* __restrict__ spk2,  // [B][H]
    const float* __restrict__ ow,    // [O][H]
    const float* __restrict__ ob,    // [O]
    float* __restrict__ out)         // [B][O]
{
    int b = blockIdx.x;
    int t = threadIdx.x;

    float p[NO];
    #pragma unroll
    for (int o = 0; o < NO; ++o) p[o] = 0.0f;

    for (int h = t; h < NH; h += 256) {
        float s = spk2[b * NH + h];
        #pragma unroll
        for (int o = 0; o < NO; ++o) p[o] += s * ow[o * NH + h];
    }

    __shared__ float red[NO][256];
    #pragma unroll
    for (int o = 0; o < NO; ++o) red[o][t] = p[o];
    __syncthreads();

    for (int off = 128; off > 0; off >>= 1) {
        if (t < off) {
            #pragma unroll
            for (int o = 0; o < NO; ++o) red[o][t] += red[o][t + off];
        }
        __syncthreads();
    }

    if (t == 0) {
        float v[NO], mx = -1e30f;
        #pragma unroll
        for (int o = 0; o < NO; ++o) { v[o] = red[o][0] + ob[o]; mx = fmaxf(mx, v[o]); }
        float sum = 0.0f;
        #pragma unroll
        for (int o = 0; o < NO; ++o) { v[o] = expf(v[o] - mx); sum += v[o]; }
        float inv = 1.0f / sum;
        #pragma unroll
        for (int o = 0; o < NO; ++o) out[b * NO + o] = v[o] * inv;
    }
}

extern "C" void kernel_launch(void* const* d_in, const int* in_sizes, int n_in,
                              void* d_out, int out_size, void* d_ws, size_t ws_size,
                              hipStream_t stream) {
    const float4* x  = (const float4*)d_in[0];  // [32][2000][512][4]
    const float*  cw = (const float*)d_in[1];   // [4]
    const float*  cb = (const float*)d_in[2];   // [1]
    const float*  hw = (const float*)d_in[3];   // [1024][512]
    const float*  hb = (const float*)d_in[4];   // [1024]
    const float*  ow = (const float*)d_in[5];   // [10][1024]
    const float*  ob = (const float*)d_in[6];   // [10]
    float* out = (float*)d_out;                 // [32][10]

    char* ws = (char*)d_ws;
    float* spk1 = (float*)(ws);                           // 32*20*512*4   = 1,310,720 B
    float* wT   = (float*)(ws + 1310720);                 // 512*1024*4    = 2,097,152 B
    float* spk2 = (float*)(ws + 1310720 + 2097152);       // 32*1024*4     =   131,072 B

    // transpose hidden_w (tiny, runs before k2; independent of k1 data)
    k_transpose<<<dim3(16, 32), dim3(32, 8), 0, stream>>>(hw, wT);

    // stage 1: conv + scan1  (the HBM-bound 524 MB read)
    k1_conv_scan<<<(NB * NG * NW) / 256, 256, 0, stream>>>(x, cw, cb, spk1);

    // stage 2+3: hidden GEMM + scan2
    k2_hidden_scan<<<NB * 4, 256, 0, stream>>>(spk1, wT, hb, spk2);

    // stage 4: output + softmax
    k3_out<<<NB, 256, 0, stream>>>(spk2, ow, ob, out);
}

// Round 2
// 170.587 us; speedup vs baseline: 1.1738x; 1.1738x over previous
//
#include <hip/hip_runtime.h>
#include <hip/hip_bf16.h>

typedef float f32x4 __attribute__((ext_vector_type(4)));

#define NB 32      // batch
#define NT 2000    // time
#define NW 512     // width
#define NG 20      // groups (T / NUM_STEPS)
#define NS 100     // NUM_STEPS
#define NH 1024    // hidden
#define NO 10      // outputs
#define BETA 0.95f
#define THRESH 1.0f

// ---------------- Kernel 1: fused 1x1 conv + 100-step leaky scan ----------------
// One thread per (b,g,w). Explicit 2x10 register double-buffer keeps 10-20
// nontemporal float4 loads in flight per wave (MLP deep enough to saturate HBM).
// All buffer indices are compile-time constants (no scratch spill).
__global__ __launch_bounds__(256) void k1_conv_scan(
    const f32x4* __restrict__ x,    // [B][T][W] of float4 (C=4 innermost)
    const float* __restrict__ cw,   // [4]
    const float* __restrict__ cb,   // [1]
    float* __restrict__ spk1)       // [B][G][W]
{
    int idx = blockIdx.x * 256 + threadIdx.x;      // 0 .. B*G*W-1
    int w = idx & (NW - 1);
    int g = (idx >> 9) % NG;
    int b = idx / (NG * NW);

    float w0 = cw[0], w1 = cw[1], w2 = cw[2], w3 = cw[3];
    float bias = cb[0];

    const f32x4* xp = x + ((size_t)(b * NT + g * NS) * NW + w);

    f32x4 A[10], B[10];
    float mem = 0.0f;

#define LOAD10(dst, S0)                                                         \
    {                                                                           \
        _Pragma("unroll")                                                       \
        for (int j = 0; j < 10; ++j)                                            \
            dst[j] = __builtin_nontemporal_load(xp + (size_t)((S0) + j) * NW);  \
    }
#define STEP10(src)                                                             \
    {                                                                           \
        _Pragma("unroll")                                                       \
        for (int j = 0; j < 10; ++j) {                                          \
            f32x4 v = src[j];                                                   \
            float f = fmaf(v[0], w0, fmaf(v[1], w1,                             \
                      fmaf(v[2], w2, fmaf(v[3], w3, bias))));                   \
            float base = fmaf(BETA, mem, f);                                    \
            mem = (mem > THRESH) ? 0.0f : base;                                 \
        }                                                                       \
    }

    LOAD10(A, 0)
    LOAD10(B, 10) STEP10(A)
    LOAD10(A, 20) STEP10(B)
    LOAD10(B, 30) STEP10(A)
    LOAD10(A, 40) STEP10(B)
    LOAD10(B, 50) STEP10(A)
    LOAD10(A, 60) STEP10(B)
    LOAD10(B, 70) STEP10(A)
    LOAD10(A, 80) STEP10(B)
    LOAD10(B, 90) STEP10(A)
    STEP10(B)
#undef LOAD10
#undef STEP10

    spk1[idx] = (mem > THRESH) ? 1.0f : 0.0f;   // final-step spike
}

// ---------------- Transpose hidden_w (1024x512 -> 512x1024) ----------------
__global__ __launch_bounds__(256) void k_transpose(
    const float* __restrict__ wsrc,  // [H][W]
    float* __restrict__ wT)          // [W][H]
{
    __shared__ float tile[32][33];
    int bk = blockIdx.x;             // 16 tiles over W
    int bh = blockIdx.y;             // 32 tiles over H
    int tx = threadIdx.x;            // 0..31
    int ty = threadIdx.y;            // 0..7
    #pragma unroll
    for (int j = 0; j < 4; ++j)
        tile[ty + j * 8][tx] = wsrc[(bh * 32 + ty + j * 8) * NW + bk * 32 + tx];
    __syncthreads();
    #pragma unroll
    for (int j = 0; j < 4; ++j)
        wT[(bk * 32 + ty + j * 8) * NH + bh * 32 + tx] = tile[tx][ty + j * 8];
}

// ---------------- Kernel 2: hidden GEMM (over g in registers) + 20-step scan ----
// 256 blocks x 128 threads: all 256 CUs active. One thread per (b,h); b from
// blockIdx only -> spk1 float4 loads are wave-uniform (scalar-load path).
__global__ __launch_bounds__(128) void k2_hidden_scan(
    const float* __restrict__ spk1,  // [B][G][W]
    const float* __restrict__ wT,    // [W][H]
    const float* __restrict__ hb,    // [H]
    float* __restrict__ spk2)        // [B][H]
{
    int b = blockIdx.x >> 3;                          // 8 blocks per b
    int h = ((blockIdx.x & 7) << 7) + threadIdx.x;    // 0..1023

    const float* sp = spk1 + (size_t)b * NG * NW;     // uniform base

    float acc[NG];
    #pragma unroll
    for (int g = 0; g < NG; ++g) acc[g] = 0.0f;

    for (int kk = 0; kk < NW; kk += 4) {
        float a0 = wT[(kk + 0) * NH + h];
        float a1 = wT[(kk + 1) * NH + h];
        float a2 = wT[(kk + 2) * NH + h];
        float a3 = wT[(kk + 3) * NH + h];
        #pragma unroll
        for (int g = 0; g < NG; ++g) {
            float4 u = *(const float4*)(sp + g * NW + kk);  // uniform -> s_load
            acc[g] += u.x * a0 + u.y * a1 + u.z * a2 + u.w * a3;
        }
    }

    float hbias = hb[h];
    float mem = 0.0f;
    #pragma unroll
    for (int g = 0; g < NG; ++g) {
        float xin = acc[g] + hbias;
        float base = BETA * mem + xin;
        mem = (mem > THRESH) ? 0.0f : base;
    }
    spk2[b * NH + h] = (mem > THRESH) ? 1.0f : 0.0f;
}

// ---------------- Kernel 3: output layer + softmax ----------------
__global__ __launch_bounds__(256) void k3_out(
    const float* __restrict__ spk2,  // [B][H]
    const float* __restrict__ ow,    // [O][H]
    const float* __restrict__ ob,    // [O]
    float* __restrict__ out)         // [B][O]
{
    int b = blockIdx.x;
    int t = threadIdx.x;

    float p[NO];
    #pragma unroll
    for (int o = 0; o < NO; ++o) p[o] = 0.0f;

    for (int h = t; h < NH; h += 256) {
        float s = spk2[b * NH + h];
        #pragma unroll
        for (int o = 0; o < NO; ++o) p[o] += s * ow[o * NH + h];
    }

    __shared__ float red[NO][256];
    #pragma unroll
    for (int o = 0; o < NO; ++o) red[o][t] = p[o];
    __syncthreads();

    for (int off = 128; off > 0; off >>= 1) {
        if (t < off) {
            #pragma unroll
            for (int o = 0; o < NO; ++o) red[o][t] += red[o][t + off];
        }
        __syncthreads();
    }

    if (t == 0) {
        float v[NO], mx = -1e30f;
        #pragma unroll
        for (int o = 0; o < NO; ++o) { v[o] = red[o][0] + ob[o]; mx = fmaxf(mx, v[o]); }
        float sum = 0.0f;
        #pragma unroll
        for (int o = 0; o < NO; ++o) { v[o] = expf(v[o] - mx); sum += v[o]; }
        float inv = 1.0f / sum;
        #pragma unroll
        for (int o = 0; o < NO; ++o) out[b * NO + o] = v[o] * inv;
    }
}

extern "C" void kernel_launch(void* const* d_in, const int* in_sizes, int n_in,
                              void* d_out, int out_size, void* d_ws, size_t ws_size,
                              hipStream_t stream) {
    const f32x4*  x  = (const f32x4*)d_in[0];   // [32][2000][512][4]
    const float*  cw = (const float*)d_in[1];   // [4]
    const float*  cb = (const float*)d_in[2];   // [1]
    const float*  hw = (const float*)d_in[3];   // [1024][512]
    const float*  hb = (const float*)d_in[4];   // [1024]
    const float*  ow = (const float*)d_in[5];   // [10][1024]
    const float*  ob = (const float*)d_in[6];   // [10]
    float* out = (float*)d_out;                 // [32][10]

    char* ws = (char*)d_ws;
    float* spk1 = (float*)(ws);                           // 32*20*512*4   = 1,310,720 B
    float* wT   = (float*)(ws + 1310720);                 // 512*1024*4    = 2,097,152 B
    float* spk2 = (float*)(ws + 1310720 + 2097152);       // 32*1024*4     =   131,072 B

    // transpose hidden_w (tiny; independent of k1 data)
    k_transpose<<<dim3(16, 32), dim3(32, 8), 0, stream>>>(hw, wT);

    // stage 1: conv + scan1  (the HBM-bound 524 MB read)
    k1_conv_scan<<<(NB * NG * NW) / 256, 256, 0, stream>>>(x, cw, cb, spk1);

    // stage 2+3: hidden GEMM + scan2
    k2_hidden_scan<<<NB * 8, 128, 0, stream>>>(spk1, wT, hb, spk2);

    // stage 4: output + softmax
    k3_out<<<NB, 256, 0, stream>>>(spk2, ow, ob, out);
}

// Round 3
// 134.534 us; speedup vs baseline: 1.4884x; 1.2680x over previous
//
#include <hip/hip_runtime.h>
#include <hip/hip_bf16.h>

typedef float f32x4 __attribute__((ext_vector_type(4)));

#define NB 32      // batch
#define NT 2000    // time
#define NW 512     // width
#define NG 20      // groups (T / NUM_STEPS)
#define NS 100     // NUM_STEPS
#define NH 1024    // hidden
#define NO 10      // outputs
#define BETA 0.95f
#define THRESH 1.0f

// ---------------- Kernel 1: fused 1x1 conv + 100-step leaky scan ----------------
// Block covers one (b,g,half-row): base pointer derived ONLY from blockIdx ->
// wave-uniform SGPR base + small 32-bit per-lane offsets. 10+10 register
// double-buffer of nontemporal float4 loads keeps HBM queue full.
__global__ __launch_bounds__(256) void k1_conv_scan(
    const f32x4* __restrict__ x,    // [B][T][W] of float4 (C=4 innermost)
    const float* __restrict__ cw,   // [4]
    const float* __restrict__ cb,   // [1]
    float* __restrict__ spk1)       // [B][G][W]
{
    int bid = blockIdx.x;           // 0..1279
    int half = bid & 1;             // which half of the 512-wide row
    int bg = bid >> 1;              // 0..639
    int g = bg % NG;
    int b = bg / NG;
    int tid = threadIdx.x;          // 0..255

    // uniform base (SGPR), per-lane offset = tid + s*512 (32-bit)
    const f32x4* __restrict__ base =
        x + ((size_t)(b * NT + g * NS) * NW + half * 256);

    float w0 = cw[0], w1 = cw[1], w2 = cw[2], w3 = cw[3];
    float bias = cb[0];

    f32x4 A[10], B[10];
    float mem = 0.0f;

#define LOAD10(dst, S0)                                                        \
    {                                                                          \
        _Pragma("unroll")                                                      \
        for (int j = 0; j < 10; ++j)                                           \
            dst[j] = __builtin_nontemporal_load(base + (tid + ((S0) + j) * NW)); \
    }
#define STEP10(src)                                                            \
    {                                                                          \
        _Pragma("unroll")                                                      \
        for (int j = 0; j < 10; ++j) {                                         \
            f32x4 v = src[j];                                                  \
            float f = fmaf(v[0], w0, fmaf(v[1], w1,                            \
                      fmaf(v[2], w2, fmaf(v[3], w3, bias))));                  \
            float base_m = fmaf(BETA, mem, f);                                 \
            mem = (mem > THRESH) ? 0.0f : base_m;                              \
        }                                                                      \
    }

    LOAD10(A, 0)
    LOAD10(B, 10) STEP10(A)
    LOAD10(A, 20) STEP10(B)
    LOAD10(B, 30) STEP10(A)
    LOAD10(A, 40) STEP10(B)
    LOAD10(B, 50) STEP10(A)
    LOAD10(A, 60) STEP10(B)
    LOAD10(B, 70) STEP10(A)
    LOAD10(A, 80) STEP10(B)
    LOAD10(B, 90) STEP10(A)
    STEP10(B)
#undef LOAD10
#undef STEP10

    spk1[(b * NG + g) * NW + half * 256 + tid] = (mem > THRESH) ? 1.0f : 0.0f;
}

// ---------------- Transpose hidden_w (1024x512 -> 512x1024) ----------------
__global__ __launch_bounds__(256) void k_transpose(
    const float* __restrict__ wsrc,  // [H][W]
    float* __restrict__ wT)          // [W][H]
{
    __shared__ float tile[32][33];
    int bk = blockIdx.x;             // 16 tiles over W
    int bh = blockIdx.y;             // 32 tiles over H
    int tx = threadIdx.x;            // 0..31
    int ty = threadIdx.y;            // 0..7
    #pragma unroll
    for (int j = 0; j < 4; ++j)
        tile[ty + j * 8][tx] = wsrc[(bh * 32 + ty + j * 8) * NW + bk * 32 + tx];
    __syncthreads();
    #pragma unroll
    for (int j = 0; j < 4; ++j)
        wT[(bk * 32 + ty + j * 8) * NH + bh * 32 + tx] = tile[tx][ty + j * 8];
}

// ---------------- Kernel 2: hidden GEMM (4-way k-split) + 20-step scan ----------
// 512 blocks x 256 threads (8 waves/CU). Thread = (b, h in 64-range, k-chunk).
// Per wave: b, chunk, g, kk all uniform -> spk1 reads take the s_load path.
// 4 k-chunk partials combined in LDS; wave 0 runs the scan.
__global__ __launch_bounds__(256) void k2_hidden_scan(
    const float* __restrict__ spk1,  // [B][G][W]
    const float* __restrict__ wT,    // [W][H]
    const float* __restrict__ hb,    // [H]
    float* __restrict__ spk2)        // [B][H]
{
    int bid = blockIdx.x;            // 0..511
    int b = bid >> 4;                // 0..31
    int hgrp = bid & 15;             // 0..15
    int t = threadIdx.x;
    int lane = t & 63;
    int c = t >> 6;                  // k-chunk 0..3
    int h = hgrp * 64 + lane;

    const float* __restrict__ sp = spk1 + (size_t)b * NG * NW;  // uniform

    float acc[NG];
    #pragma unroll
    for (int g = 0; g < NG; ++g) acc[g] = 0.0f;

    int k0 = c * 128;
    for (int kk = k0; kk < k0 + 128; kk += 4) {
        float a0 = wT[(kk + 0) * NH + h];
        float a1 = wT[(kk + 1) * NH + h];
        float a2 = wT[(kk + 2) * NH + h];
        float a3 = wT[(kk + 3) * NH + h];
        #pragma unroll
        for (int g = 0; g < NG; ++g) {
            float4 u = *(const float4*)(sp + g * NW + kk);  // uniform -> s_load
            acc[g] += u.x * a0 + u.y * a1 + u.z * a2 + u.w * a3;
        }
    }

    __shared__ float red[4][NG][64];
    #pragma unroll
    for (int g = 0; g < NG; ++g) red[c][g][lane] = acc[g];
    __syncthreads();

    if (t < 64) {
        float hbias = hb[h];
        float mem = 0.0f;
        #pragma unroll
        for (int g = 0; g < NG; ++g) {
            float xin = red[0][g][lane] + red[1][g][lane]
                      + red[2][g][lane] + red[3][g][lane] + hbias;
            float base = fmaf(BETA, mem, xin);
            mem = (mem > THRESH) ? 0.0f : base;
        }
        spk2[b * NH + h] = (mem > THRESH) ? 1.0f : 0.0f;
    }
}

// ---------------- Kernel 3: output layer + softmax ----------------
__global__ __launch_bounds__(256) void k3_out(
    const float* __restrict__ spk2,  // [B][H]
    const float* __restrict__ ow,    // [O][H]
    const float* __restrict__ ob,    // [O]
    float* __restrict__ out)         // [B][O]
{
    int b = blockIdx.x;
    int t = threadIdx.x;

    float p[NO];
    #pragma unroll
    for (int o = 0; o < NO; ++o) p[o] = 0.0f;

    for (int h = t; h < NH; h += 256) {
        float s = spk2[b * NH + h];
        #pragma unroll
        for (int o = 0; o < NO; ++o) p[o] += s * ow[o * NH + h];
    }

    __shared__ float red[NO][256];
    #pragma unroll
    for (int o = 0; o < NO; ++o) red[o][t] = p[o];
    __syncthreads();

    for (int off = 128; off > 0; off >>= 1) {
        if (t < off) {
            #pragma unroll
            for (int o = 0; o < NO; ++o) red[o][t] += red[o][t + off];
        }
        __syncthreads();
    }

    if (t == 0) {
        float v[NO], mx = -1e30f;
        #pragma unroll
        for (int o = 0; o < NO; ++o) { v[o] = red[o][0] + ob[o]; mx = fmaxf(mx, v[o]); }
        float sum = 0.0f;
        #pragma unroll
        for (int o = 0; o < NO; ++o) { v[o] = expf(v[o] - mx); sum += v[o]; }
        float inv = 1.0f / sum;
        #pragma unroll
        for (int o = 0; o < NO; ++o) out[b * NO + o] = v[o] * inv;
    }
}

extern "C" void kernel_launch(void* const* d_in, const int* in_sizes, int n_in,
                              void* d_out, int out_size, void* d_ws, size_t ws_size,
                              hipStream_t stream) {
    const f32x4*  x  = (const f32x4*)d_in[0];   // [32][2000][512][4]
    const float*  cw = (const float*)d_in[1];   // [4]
    const float*  cb = (const float*)d_in[2];   // [1]
    const float*  hw = (const float*)d_in[3];   // [1024][512]
    const float*  hb = (const float*)d_in[4];   // [1024]
    const float*  ow = (const float*)d_in[5];   // [10][1024]
    const float*  ob = (const float*)d_in[6];   // [10]
    float* out = (float*)d_out;                 // [32][10]

    char* ws = (char*)d_ws;
    float* spk1 = (float*)(ws);                           // 32*20*512*4   = 1,310,720 B
    float* wT   = (float*)(ws + 1310720);                 // 512*1024*4    = 2,097,152 B
    float* spk2 = (float*)(ws + 1310720 + 2097152);       // 32*1024*4     =   131,072 B

    // transpose hidden_w (tiny; independent of k1 data)
    k_transpose<<<dim3(16, 32), dim3(32, 8), 0, stream>>>(hw, wT);

    // stage 1: conv + scan1  (the HBM-bound 524 MB read)
    k1_conv_scan<<<(NB * NG * NW) / 256, 256, 0, stream>>>(x, cw, cb, spk1);

    // stage 2+3: hidden GEMM (4-way k-split) + scan2
    k2_hidden_scan<<<NB * 16, 256, 0, stream>>>(spk1, wT, hb, spk2);

    // stage 4: output + softmax
    k3_out<<<NB, 256, 0, stream>>>(spk2, ow, ob, out);
}